// Round 2
// baseline (916.349 us; speedup 1.0000x reference)
//
#include <hip/hip_runtime.h>
#include <math.h>

typedef __bf16 bf16_t;
typedef __bf16 bf16x8_t __attribute__((ext_vector_type(8)));
typedef __bf16 bf16x4_t __attribute__((ext_vector_type(4)));
typedef float f32x4_t __attribute__((ext_vector_type(4)));
typedef int i32x4_t __attribute__((ext_vector_type(4)));

#define MFMA(a, b, c) __builtin_amdgcn_mfma_f32_16x16x32_bf16((a), (b), (c), 0, 0, 0)

// ---- workspace layout (bytes) ---- (total 401408, same proven footprint as R1)
#define WS_WQKV 0u           // 576*192 bf16 = 221184
#define WS_WPROJ 221184u     // 192*192 bf16 = 73728
#define WS_QBIAS 294912u     // 576 f32 = 2304
#define WS_SCALE 297216u     // 6 f32
#define WS_TBL 297472u       // 225*6 f32 = 5400
#define WS_B16T 303104u      // 6*64*64 f32 = 98304 -> end 401408  [h][key][query]

static __device__ __forceinline__ unsigned pk2(float a, float b) {
  unsigned short ua = __builtin_bit_cast(unsigned short, (bf16_t)a);
  unsigned short ub = __builtin_bit_cast(unsigned short, (bf16_t)b);
  return (unsigned)ua | ((unsigned)ub << 16);
}

// ============ K1: CPB table: tbl[t][h] ============
__global__ __launch_bounds__(64) void cpb_table_kernel(
    const float* __restrict__ w1, const float* __restrict__ b1,
    const float* __restrict__ w2, float* __restrict__ tbl) {
  int t = blockIdx.x;  // 0..224
  int lane = threadIdx.x;
  int dh = t / 15 - 7, dw = t % 15 - 7;
  float th = (float)dh * (8.0f / 7.0f);
  float tw = (float)dw * (8.0f / 7.0f);
  float c0 = copysignf(log2f(fabsf(th) + 1.0f) / 3.0f, th);
  float c1 = copysignf(log2f(fabsf(tw) + 1.0f) / 3.0f, tw);
  float acc[6] = {0.f, 0.f, 0.f, 0.f, 0.f, 0.f};
  for (int k = lane; k < 512; k += 64) {
    float hv = fmaxf(w1[2 * k] * c0 + w1[2 * k + 1] * c1 + b1[k], 0.0f);
#pragma unroll
    for (int hh = 0; hh < 6; ++hh) acc[hh] += hv * w2[hh * 512 + k];
  }
#pragma unroll
  for (int hh = 0; hh < 6; ++hh) {
#pragma unroll
    for (int m = 1; m < 64; m <<= 1) acc[hh] += __shfl_xor(acc[hh], m, 64);
  }
  if (lane == 0) {
#pragma unroll
    for (int hh = 0; hh < 6; ++hh) tbl[t * 6 + hh] = acc[hh];
  }
}

// ============ K2: weights->bf16, qkv bias, scales, transposed sigmoid bias table ============
__global__ __launch_bounds__(256) void prep_kernel(
    const float* __restrict__ qkv_w, const float* __restrict__ proj_w,
    const float* __restrict__ q_bias, const float* __restrict__ v_bias,
    const float* __restrict__ logit_scale, const float* __restrict__ tbl,
    bf16_t* __restrict__ wqkv, bf16_t* __restrict__ wproj,
    float* __restrict__ qbias, float* __restrict__ scalev,
    float* __restrict__ b16T) {
  int id = blockIdx.x * 256 + threadIdx.x;
  if (id < 110592) {
    wqkv[id] = (bf16_t)qkv_w[id];
  } else if (id < 147456) {
    int i = id - 110592;
    wproj[i] = (bf16_t)proj_w[i];
  } else if (id < 148032) {
    int i = id - 147456;
    float bv = (i < 192) ? q_bias[i] : ((i < 384) ? 0.0f : v_bias[i - 384]);
    qbias[i] = bv;
  } else if (id < 148038) {
    int hh = id - 148032;
    scalev[hh] = expf(fminf(logit_scale[hh], logf(100.0f)));
  } else if (id < 246342) {
    int i = id - 148038;  // h*4096 + key*64 + query
    int hh = i >> 12;
    int key = (i >> 6) & 63;
    int n = i & 63;  // query
    int i1 = n >> 3, j1 = n & 7, i2 = key >> 3, j2 = key & 7;
    int rpi = (i1 - i2 + 7) * 15 + (j1 - j2 + 7);
    float v = tbl[rpi * 6 + hh];
    b16T[i] = 16.0f / (1.0f + __expf(-v));
  }
}

// ============ main fused kernel ============
// 384 threads = 6 waves = (h3 in 0..2) x (token-half s); 2 rounds of 3 heads.
// LDS (74.0 KB -> 2 blocks/CU):
//  [0,25600)      xs  : x bf16 64 x stride200   } os (64 x stride200) aliases after round-2 QKV
//  [25600,53248)  qk  : 3 x (64 x stride72): cols 0..31 = q, 32..63 = k
//  [53248,67072)  vts : 3 x (32 x stride72) [chan][token]
//  [67072,75776)  mskT: 64 x stride68 bf16, [key][query]
__global__ __launch_bounds__(384, 3) void wattn_kernel(
    const float* __restrict__ x, const float* __restrict__ mask,
    const bf16_t* __restrict__ wqkv, const bf16_t* __restrict__ wproj,
    const float* __restrict__ qbias, const float* __restrict__ scalev,
    const float* __restrict__ b16T, const float* __restrict__ proj_b,
    float* __restrict__ out, int nw) {
  __shared__ __align__(16) char smem[75776];
  bf16_t* xs = (bf16_t*)smem;
  bf16_t* qk = (bf16_t*)(smem + 25600);
  bf16_t* vts = (bf16_t*)(smem + 53248);
  bf16_t* mskT = (bf16_t*)(smem + 67072);
  bf16_t* os = (bf16_t*)smem;

  const int tid = threadIdx.x;
  const int wave = tid >> 6, lane = tid & 63;
  const int h3 = wave >> 1, s = wave & 1;
  const int quad = lane >> 4, col = lane & 15;
  const int b = blockIdx.x;
  const bool hi32 = (lane & 32) != 0;
  const int psrc0 = ((lane & 16) << 1) + col;  // (quad&1)*32 + col
  const int psrc1 = psrc0 + 16;
  const f32x4_t zz = {0.f, 0.f, 0.f, 0.f};

  // ---- stage x (fp32 -> bf16) ----
  const float4* xg = (const float4*)(x + (size_t)b * 12288);
#pragma unroll
  for (int it = 0; it < 8; ++it) {
    int i = it * 384 + tid;
    float4 v = xg[i];
    int row = i / 48;
    int c = (i - row * 48) * 4;
    bf16x4_t pkv = {(bf16_t)v.x, (bf16_t)v.y, (bf16_t)v.z, (bf16_t)v.w};
    *(bf16x4_t*)(xs + row * 200 + c) = pkv;
  }
  // ---- stage mask transposed, bf16 ----
  const float* mg = mask + (size_t)(b % nw) * 4096;
  for (int i = tid; i < 4096; i += 384) {
    int n = i >> 6, m = i & 63;
    mskT[m * 68 + n] = (bf16_t)mg[i];
  }
  __syncthreads();  // B1

  f32x4_t oheld[2][2][2];
  bf16_t* qkh = qk + h3 * 4608;
  bf16_t* vtsh = vts + h3 * 2304;

#pragma unroll
  for (int r = 0; r < 2; ++r) {
    const int h = r * 3 + h3;
    if (r == 1) __syncthreads();  // round-1 attn readers done before overwriting qk/vts
    const float sc_h = scalev[h];

    // ---- QKV GEMM: head h cols, token-half s rows ----
#pragma unroll
    for (int g = 0; g < 3; ++g) {
      const int nbase = g * 192 + h * 32;
      f32x4_t a00 = zz, a01 = zz, a10 = zz, a11 = zz;
      const bf16_t* wb = wqkv + (size_t)nbase * 192;
#pragma unroll
      for (int kk = 0; kk < 6; ++kk) {
        const int k0 = kk * 32 + quad * 8;
        bf16x8_t fa0 = *(const bf16x8_t*)(xs + (s * 32 + col) * 200 + k0);
        bf16x8_t fa1 = *(const bf16x8_t*)(xs + (s * 32 + 16 + col) * 200 + k0);
        bf16x8_t fb0 = *(const bf16x8_t*)(wb + (size_t)col * 192 + k0);
        bf16x8_t fb1 = *(const bf16x8_t*)(wb + (size_t)(16 + col) * 192 + k0);
        a00 = MFMA(fa0, fb0, a00);
        a01 = MFMA(fa0, fb1, a01);
        a10 = MFMA(fa1, fb0, a10);
        a11 = MFMA(fa1, fb1, a11);
      }
      float bn0 = qbias[nbase + col];
      float bn1 = qbias[nbase + 16 + col];
      if (g < 2) {
        float mult = (g == 0) ? sc_h : 1.0f;
        const int goff = g * 32;
#pragma unroll
        for (int mt = 0; mt < 2; ++mt) {
          f32x4_t va = mt ? a10 : a00;
          f32x4_t vb = mt ? a11 : a01;
#pragma unroll
          for (int rr = 0; rr < 4; ++rr) {
            float v0 = va[rr] + bn0, v1 = vb[rr] + bn1;
            float ss2 = v0 * v0 + v1 * v1;
            ss2 += __shfl_xor(ss2, 1, 64);
            ss2 += __shfl_xor(ss2, 2, 64);
            ss2 += __shfl_xor(ss2, 4, 64);
            ss2 += __shfl_xor(ss2, 8, 64);
            float inv = mult / fmaxf(sqrtf(ss2), 1e-12f);
            int token = s * 32 + mt * 16 + quad * 4 + rr;
            qkh[token * 72 + goff + col] = (bf16_t)(v0 * inv);
            qkh[token * 72 + goff + 16 + col] = (bf16_t)(v1 * inv);
          }
        }
      } else {
#pragma unroll
        for (int mt = 0; mt < 2; ++mt) {
          f32x4_t va = mt ? a10 : a00;
          f32x4_t vb = mt ? a11 : a01;
          int tb = s * 32 + mt * 16 + quad * 4;
          bf16x4_t p0 = {(bf16_t)(va[0] + bn0), (bf16_t)(va[1] + bn0),
                         (bf16_t)(va[2] + bn0), (bf16_t)(va[3] + bn0)};
          bf16x4_t p1 = {(bf16_t)(vb[0] + bn1), (bf16_t)(vb[1] + bn1),
                         (bf16_t)(vb[2] + bn1), (bf16_t)(vb[3] + bn1)};
          *(bf16x4_t*)(vtsh + col * 72 + tb) = p0;
          *(bf16x4_t*)(vtsh + (16 + col) * 72 + tb) = p1;
        }
      }
    }
    __syncthreads();  // qk/vts of both halves visible

    // ---- S^T = K @ Q^T (keys = M rows, this wave's queries = N cols) ----
    f32x4_t sacc[4][2];
    {
      bf16x8_t qf0 = *(const bf16x8_t*)(qkh + (s * 32 + col) * 72 + quad * 8);
      bf16x8_t qf1 = *(const bf16x8_t*)(qkh + (s * 32 + 16 + col) * 72 + quad * 8);
#pragma unroll
      for (int mt = 0; mt < 4; ++mt) {
        bf16x8_t kf = *(const bf16x8_t*)(qkh + (mt * 16 + col) * 72 + 32 + quad * 8);
        sacc[mt][0] = MFMA(kf, qf0, zz);
        sacc[mt][1] = MFMA(kf, qf1, zz);
      }
    }

    // ---- bias + mask + softmax (per query col; keys distributed mt,rr in-lane + quad) ----
    const float* bT = b16T + h * 4096;
    float pv[4][2][4];
#pragma unroll
    for (int nt = 0; nt < 2; ++nt) {
      int qg = s * 32 + nt * 16 + col;
      float vals[16];
#pragma unroll
      for (int mt = 0; mt < 4; ++mt)
#pragma unroll
        for (int rr = 0; rr < 4; ++rr) {
          int key = mt * 16 + quad * 4 + rr;
          vals[mt * 4 + rr] = sacc[mt][nt][rr] + bT[key * 64 + qg] + (float)mskT[key * 68 + qg];
        }
      float mx = vals[0];
#pragma unroll
      for (int i = 1; i < 16; ++i) mx = fmaxf(mx, vals[i]);
      mx = fmaxf(mx, __shfl_xor(mx, 16, 64));
      mx = fmaxf(mx, __shfl_xor(mx, 32, 64));
      float sm = 0.f;
#pragma unroll
      for (int i = 0; i < 16; ++i) {
        vals[i] = __expf(vals[i] - mx);
        sm += vals[i];
      }
      sm += __shfl_xor(sm, 16, 64);
      sm += __shfl_xor(sm, 32, 64);
      float inv = 1.0f / sm;
#pragma unroll
      for (int mt = 0; mt < 4; ++mt)
#pragma unroll
        for (int rr = 0; rr < 4; ++rr) pv[mt][nt][rr] = vals[mt * 4 + rr] * inv;
    }

    // ---- pack P^T (C-layout) and assemble PV B-frags in-register via bpermute ----
    unsigned pk01[4][2], pk23[4][2];
#pragma unroll
    for (int mt = 0; mt < 4; ++mt)
#pragma unroll
      for (int nt = 0; nt < 2; ++nt) {
        pk01[mt][nt] = pk2(pv[mt][nt][0], pv[mt][nt][1]);
        pk23[mt][nt] = pk2(pv[mt][nt][2], pv[mt][nt][3]);
      }

    f32x4_t oc[2][2] = {{zz, zz}, {zz, zz}};
#pragma unroll
    for (int kk = 0; kk < 2; ++kk) {
      bf16x8_t bq[2];
#pragma unroll
      for (int nt = 0; nt < 2; ++nt) {
        unsigned a0 = __shfl(pk01[kk * 2][nt], psrc0, 64);
        unsigned b0 = __shfl(pk01[kk * 2 + 1][nt], psrc0, 64);
        unsigned a1 = __shfl(pk23[kk * 2][nt], psrc0, 64);
        unsigned b1 = __shfl(pk23[kk * 2 + 1][nt], psrc0, 64);
        unsigned a2 = __shfl(pk01[kk * 2][nt], psrc1, 64);
        unsigned b2 = __shfl(pk01[kk * 2 + 1][nt], psrc1, 64);
        unsigned a3 = __shfl(pk23[kk * 2][nt], psrc1, 64);
        unsigned b3 = __shfl(pk23[kk * 2 + 1][nt], psrc1, 64);
        i32x4_t di = {(int)(hi32 ? b0 : a0), (int)(hi32 ? b1 : a1),
                      (int)(hi32 ? b2 : a2), (int)(hi32 ? b3 : a3)};
        bq[nt] = __builtin_bit_cast(bf16x8_t, di);
      }
#pragma unroll
      for (int ct = 0; ct < 2; ++ct) {
        bf16x8_t vf = *(const bf16x8_t*)(vtsh + (ct * 16 + col) * 72 + kk * 32 + quad * 8);
        oc[ct][0] = MFMA(vf, bq[0], oc[ct][0]);
        oc[ct][1] = MFMA(vf, bq[1], oc[ct][1]);
      }
    }
#pragma unroll
    for (int ct = 0; ct < 2; ++ct)
#pragma unroll
      for (int nt = 0; nt < 2; ++nt) oheld[r][ct][nt] = oc[ct][nt];
  }

  // ---- stage O (aliases xs; safe: all xs reads ended before round-2 post-QKV barrier) ----
#pragma unroll
  for (int r2 = 0; r2 < 2; ++r2) {
    int hh = r2 * 3 + h3;
#pragma unroll
    for (int ct = 0; ct < 2; ++ct)
#pragma unroll
      for (int nt = 0; nt < 2; ++nt) {
        f32x4_t o = oheld[r2][ct][nt];
        int token = s * 32 + nt * 16 + col;
        int cb = hh * 32 + ct * 16 + quad * 4;
        bf16x4_t pkk = {(bf16_t)o[0], (bf16_t)o[1], (bf16_t)o[2], (bf16_t)o[3]};
        *(bf16x4_t*)(os + token * 200 + cb) = pkk;
      }
  }
  __syncthreads();  // full O visible

  // ---- proj: out = O @ Wp^T + b (wave covers 32 out-cols, all 64 tokens) ----
  const int cb = wave * 32;
  f32x4_t pr[4][2];
#pragma unroll
  for (int mt = 0; mt < 4; ++mt) {
    pr[mt][0] = zz;
    pr[mt][1] = zz;
  }
#pragma unroll
  for (int kk = 0; kk < 6; ++kk) {
    int k0 = kk * 32 + quad * 8;
    bf16x8_t fb0 = *(const bf16x8_t*)(wproj + (size_t)(cb + col) * 192 + k0);
    bf16x8_t fb1 = *(const bf16x8_t*)(wproj + (size_t)(cb + 16 + col) * 192 + k0);
#pragma unroll
    for (int mt = 0; mt < 4; ++mt) {
      bf16x8_t fa = *(const bf16x8_t*)(os + (mt * 16 + col) * 200 + k0);
      pr[mt][0] = MFMA(fa, fb0, pr[mt][0]);
      pr[mt][1] = MFMA(fa, fb1, pr[mt][1]);
    }
  }
  float pb0 = proj_b[cb + col], pb1 = proj_b[cb + 16 + col];
  float* og = out + (size_t)b * 12288;
#pragma unroll
  for (int mt = 0; mt < 4; ++mt)
#pragma unroll
    for (int rr = 0; rr < 4; ++rr) {
      int token = mt * 16 + quad * 4 + rr;
      og[token * 192 + cb + col] = pr[mt][0][rr] + pb0;
      og[token * 192 + cb + 16 + col] = pr[mt][1][rr] + pb1;
    }
}

extern "C" void kernel_launch(void* const* d_in, const int* in_sizes, int n_in,
                              void* d_out, int out_size, void* d_ws, size_t ws_size,
                              hipStream_t stream) {
  const float* x = (const float*)d_in[0];
  const float* mask = (const float*)d_in[1];
  const float* qkv_w = (const float*)d_in[2];
  const float* q_bias = (const float*)d_in[3];
  const float* v_bias = (const float*)d_in[4];
  const float* logit_scale = (const float*)d_in[5];
  const float* cpb_w1 = (const float*)d_in[6];
  const float* cpb_b1 = (const float*)d_in[7];
  const float* cpb_w2 = (const float*)d_in[8];
  const float* proj_w = (const float*)d_in[9];
  const float* proj_b = (const float*)d_in[10];
  float* out = (float*)d_out;

  char* ws = (char*)d_ws;
  bf16_t* wqkv = (bf16_t*)(ws + WS_WQKV);
  bf16_t* wproj = (bf16_t*)(ws + WS_WPROJ);
  float* qbias = (float*)(ws + WS_QBIAS);
  float* scalev = (float*)(ws + WS_SCALE);
  float* tbl = (float*)(ws + WS_TBL);
  float* b16T = (float*)(ws + WS_B16T);

  const int nwin = in_sizes[0] / 12288;  // 4096
  const int nw = in_sizes[1] / 4096;     // 64

  cpb_table_kernel<<<dim3(225), dim3(64), 0, stream>>>(cpb_w1, cpb_b1, cpb_w2, tbl);
  prep_kernel<<<dim3(963), dim3(256), 0, stream>>>(qkv_w, proj_w, q_bias, v_bias,
                                                   logit_scale, tbl, wqkv, wproj,
                                                   qbias, scalev, b16T);
  wattn_kernel<<<dim3(nwin), dim3(384), 0, stream>>>(x, mask, wqkv, wproj, qbias,
                                                     scalev, b16T, proj_b, out, nw);
}